// Round 2
// baseline (164.908 us; speedup 1.0000x reference)
//
#include <hip/hip_runtime.h>
#include <hip/hip_bf16.h>

using bf16 = __hip_bfloat16;
typedef short short8 __attribute__((ext_vector_type(8)));
typedef float floatx4 __attribute__((ext_vector_type(4)));

#define NROWS 8192
#define DIM 512
#define ROWB 1024          // DIM * 2 bytes (bf16)
#define BM 256
#define BN 256
#define BK 64
#define NT 8               // DIM / BK

#define AS1(p) ((const __attribute__((address_space(1))) void*)(p))
#define AS3(p) ((__attribute__((address_space(3))) void*)(p))

#define S_BARRIER()   asm volatile("s_barrier" ::: "memory")
#define SCHED_FENCE() __builtin_amdgcn_sched_barrier(0)

#if __has_builtin(__builtin_amdgcn_exp2f)
#define EXP2(x) __builtin_amdgcn_exp2f(x)
#else
#define EXP2(x) exp2f(x)
#endif

// ---------------------------------------------------------------------------
// Kernel 1: per-row L2 normalize (fp32 -> bf16), per-row diag dot, zero rowsum
// ---------------------------------------------------------------------------
__global__ __launch_bounds__(256) void prep_kernel(
    const float* __restrict__ v, const float* __restrict__ u,
    bf16* __restrict__ vn, bf16* __restrict__ un,
    float* __restrict__ diag, float* __restrict__ rowsum)
{
    const int row = blockIdx.x;
    const int t = threadIdx.x;
    const float2 a = reinterpret_cast<const float2*>(v + (size_t)row * DIM)[t];
    const float2 b = reinterpret_cast<const float2*>(u + (size_t)row * DIM)[t];
    float sv = a.x * a.x + a.y * a.y;
    float su = b.x * b.x + b.y * b.y;
    float sd = a.x * b.x + a.y * b.y;
#pragma unroll
    for (int m = 32; m; m >>= 1) {
        sv += __shfl_xor(sv, m);
        su += __shfl_xor(su, m);
        sd += __shfl_xor(sd, m);
    }
    __shared__ float red[3][4];
    const int wave = t >> 6;
    if ((t & 63) == 0) { red[0][wave] = sv; red[1][wave] = su; red[2][wave] = sd; }
    __syncthreads();
    sv = red[0][0] + red[0][1] + red[0][2] + red[0][3];
    su = red[1][0] + red[1][1] + red[1][2] + red[1][3];
    sd = red[2][0] + red[2][1] + red[2][2] + red[2][3];
    const float rv = 1.0f / fmaxf(sqrtf(sv), 1e-8f);
    const float ru = 1.0f / fmaxf(sqrtf(su), 1e-8f);
    __hip_bfloat162 ov, ou;
    ov.x = __float2bfloat16(a.x * rv); ov.y = __float2bfloat16(a.y * rv);
    ou.x = __float2bfloat16(b.x * ru); ou.y = __float2bfloat16(b.y * ru);
    reinterpret_cast<__hip_bfloat162*>(vn + (size_t)row * DIM)[t] = ov;
    reinterpret_cast<__hip_bfloat162*>(un + (size_t)row * DIM)[t] = ou;
    if (t == 0) {
        diag[row] = sd * rv * ru;
        rowsum[row] = 0.0f;
    }
}

// ---------------------------------------------------------------------------
// Kernel 2: 256x256 tile, BK=64, 8 waves (2Mx4N), 4-phase schedule with
// counted vmcnt(4), T2 XOR-swizzled LDS, T5 setprio, fused exp2 rowsum.
//
// Steady-state staging (per K-tile t):
//   p0: stage (t+1).B-lo   p1: stage (t+1).B-hi   [into buf (t+1)&1]
//   p2: stage (t+2).A-lo   p3: stage (t+2).A-hi   [into buf t&1 - legal:
//       all ds_reads of tile t are issued in p0/p1 and drained by the
//       explicit lgkmcnt(0) before p1's trailing barrier]
// vmcnt invariant at end of tile t: outstanding = (t+1).A(4) + (t+1).B(4)
//   + (t+2).A(4); vmcnt(4) drains exactly tile t+1's 8 loads.
// ---------------------------------------------------------------------------
__global__ __launch_bounds__(512, 2) void simsum_kernel(
    const bf16* __restrict__ A, const bf16* __restrict__ Bm,
    float* __restrict__ rowsum)
{
    __shared__ __align__(16) char lds[131072];   // 2 x (A 32KB + B 32KB)
    const int tid  = threadIdx.x;
    const int wave = tid >> 6;
    const int lane = tid & 63;
    const int ln15 = lane & 15;
    const int lhi  = lane >> 4;
    const int swz  = (lane & 7) << 4;    // T2 read-side XOR (row&7)<<4

    // T1: bijective XCD swizzle (1024 blocks, 1024 % 8 == 0)
    const int bid  = blockIdx.x;
    const int wg   = (bid & 7) * 128 + (bid >> 3);
    const int brow = wg >> 5, bcol = wg & 31;

    const int wr = wave >> 2;            // 0..1  -> M half (128 rows)
    const int wc = wave & 3;             // 0..3  -> N quarter (64 cols)

    const char* gA = (const char*)A;
    const char* gB = (const char*)Bm;
    const int growA = brow * BM;
    const int growB = bcol * BN;

    // staging constants: thread covers slot (h*1024 + i*512 + tid);
    // row = h*128+i*64+(tid>>3); LDS dest linear; global src pre-swizzled.
    const int r0   = tid >> 3;
    const int sl16 = (((tid & 7) ^ ((tid >> 3) & 7)) << 4);

    auto stage_half = [&](const char* g, int grow0, int ldsoff, int t, int h) {
#pragma unroll
        for (int i = 0; i < 2; ++i) {
            const int row = h * 128 + i * 64 + r0;
            const char* src = g + (size_t)(grow0 + row) * ROWB + t * 128 + sl16;
            __builtin_amdgcn_global_load_lds(
                AS1(src), AS3(lds + ldsoff + (h * 1024 + i * 512 + tid) * 16),
                16, 0, 0);
        }
    };

    floatx4 acc[8][4];
#pragma unroll
    for (int m = 0; m < 8; ++m)
#pragma unroll
        for (int n = 0; n < 4; ++n)
            acc[m][n] = (floatx4){0.f, 0.f, 0.f, 0.f};

    // ---- prologue: tile0 (A+B) into buf0, tile1.A into buf1 ----
    stage_half(gA, growA, 0,     0, 0);
    stage_half(gA, growA, 0,     0, 1);
    stage_half(gB, growB, 32768, 0, 0);
    stage_half(gB, growB, 32768, 0, 1);
    stage_half(gA, growA, 65536, 1, 0);
    stage_half(gA, growA, 65536, 1, 1);
    asm volatile("s_waitcnt vmcnt(4)" ::: "memory");  // tile0's 8 landed
    S_BARRIER(); SCHED_FENCE();

#pragma unroll 2
    for (int t = 0; t < NT; ++t) {
        const int cb = (t & 1) * 65536;
        const int nb = ((t + 1) & 1) * 65536;
        const char* cA = lds + cb;
        const char* cB = lds + cb + 32768;

        // ---------------- phase 0: read B(all) + A(m0-3); stage (t+1).Blo
        short8 Bf[4][2], Alo[4][2];
#pragma unroll
        for (int n = 0; n < 4; ++n)
#pragma unroll
            for (int ks = 0; ks < 2; ++ks) {
                const int r = wc * 64 + n * 16 + ln15;
                const int c = ks * 64 + lhi * 16;
                Bf[n][ks] = *(const short8*)(cB + r * 128 + (c ^ swz));
            }
#pragma unroll
        for (int m = 0; m < 4; ++m)
#pragma unroll
            for (int ks = 0; ks < 2; ++ks) {
                const int r = wr * 128 + m * 16 + ln15;
                const int c = ks * 64 + lhi * 16;
                Alo[m][ks] = *(const short8*)(cA + r * 128 + (c ^ swz));
            }
        if (t + 1 < NT) stage_half(gB, growB, nb + 32768, t + 1, 0);
        S_BARRIER(); SCHED_FENCE();
        __builtin_amdgcn_s_setprio(1);
#pragma unroll
        for (int mm = 0; mm < 2; ++mm)
#pragma unroll
            for (int n = 0; n < 4; ++n)
#pragma unroll
                for (int ks = 0; ks < 2; ++ks)
                    acc[mm][n] = __builtin_amdgcn_mfma_f32_16x16x32_bf16(
                        Alo[mm][ks], Bf[n][ks], acc[mm][n], 0, 0, 0);
        __builtin_amdgcn_s_setprio(0);
        S_BARRIER(); SCHED_FENCE();

        // ---------------- phase 1: read A(m4-7); stage (t+1).Bhi
        short8 Ahi[4][2];
#pragma unroll
        for (int m = 0; m < 4; ++m)
#pragma unroll
            for (int ks = 0; ks < 2; ++ks) {
                const int r = wr * 128 + (m + 4) * 16 + ln15;
                const int c = ks * 64 + lhi * 16;
                Ahi[m][ks] = *(const short8*)(cA + r * 128 + (c ^ swz));
            }
        if (t + 1 < NT) stage_half(gB, growB, nb + 32768, t + 1, 1);
        S_BARRIER(); SCHED_FENCE();
        __builtin_amdgcn_s_setprio(1);
#pragma unroll
        for (int mm = 0; mm < 2; ++mm)
#pragma unroll
            for (int n = 0; n < 4; ++n)
#pragma unroll
                for (int ks = 0; ks < 2; ++ks)
                    acc[2 + mm][n] = __builtin_amdgcn_mfma_f32_16x16x32_bf16(
                        Alo[2 + mm][ks], Bf[n][ks], acc[2 + mm][n], 0, 0, 0);
        __builtin_amdgcn_s_setprio(0);
        // drain ALL of tile t's ds_reads before any wave can pass the next
        // barrier and overwrite this tile's buffer (p2/p3 staging).
        asm volatile("s_waitcnt lgkmcnt(0)" ::: "memory");
        SCHED_FENCE();
        S_BARRIER(); SCHED_FENCE();

        // ---------------- phase 2: stage (t+2).Alo into current buffer
        if (t + 2 < NT) stage_half(gA, growA, cb, t + 2, 0);
        S_BARRIER(); SCHED_FENCE();
        __builtin_amdgcn_s_setprio(1);
#pragma unroll
        for (int mm = 0; mm < 2; ++mm)
#pragma unroll
            for (int n = 0; n < 4; ++n)
#pragma unroll
                for (int ks = 0; ks < 2; ++ks)
                    acc[4 + mm][n] = __builtin_amdgcn_mfma_f32_16x16x32_bf16(
                        Ahi[mm][ks], Bf[n][ks], acc[4 + mm][n], 0, 0, 0);
        __builtin_amdgcn_s_setprio(0);
        S_BARRIER(); SCHED_FENCE();

        // ---------------- phase 3: stage (t+2).Ahi; counted vmcnt
        if (t + 2 < NT) stage_half(gA, growA, cb, t + 2, 1);
        S_BARRIER(); SCHED_FENCE();
        __builtin_amdgcn_s_setprio(1);
#pragma unroll
        for (int mm = 0; mm < 2; ++mm)
#pragma unroll
            for (int n = 0; n < 4; ++n)
#pragma unroll
                for (int ks = 0; ks < 2; ++ks)
                    acc[6 + mm][n] = __builtin_amdgcn_mfma_f32_16x16x32_bf16(
                        Ahi[2 + mm][ks], Bf[n][ks], acc[6 + mm][n], 0, 0, 0);
        __builtin_amdgcn_s_setprio(0);
        if (t < NT - 2) {
            asm volatile("s_waitcnt vmcnt(4)" ::: "memory");   // tile t+1 ready
        } else if (t == NT - 2) {
            asm volatile("s_waitcnt vmcnt(0)" ::: "memory");   // last tile: drain
        }
        S_BARRIER(); SCHED_FENCE();
    }

    // ---- epilogue: rowsum += sum_cols exp(2*sim) via exp2 ----
    // C/D layout: col = lane&15, row = (lane>>4)*4 + reg  [m89/m91 verified]
    const float C2 = 2.885390081777927f;   // 2 * log2(e)
#pragma unroll
    for (int m = 0; m < 8; ++m) {
#pragma unroll
        for (int rr = 0; rr < 4; ++rr) {
            float s = 0.f;
#pragma unroll
            for (int n = 0; n < 4; ++n)
                s += EXP2(acc[m][n][rr] * C2);
            s += __shfl_xor(s, 1);
            s += __shfl_xor(s, 2);
            s += __shfl_xor(s, 4);
            s += __shfl_xor(s, 8);
            if (ln15 == 0) {
                const int grow = growA + wr * 128 + m * 16 + lhi * 4 + rr;
                atomicAdd(&rowsum[grow], s);
            }
        }
    }
}

// ---------------------------------------------------------------------------
// Kernel 3: loss_i = log(exp(2*diag_i) + rowsum_i) - 2*diag_i
// ---------------------------------------------------------------------------
__global__ __launch_bounds__(256) void loss_kernel(
    const float* __restrict__ diag, const float* __restrict__ rowsum,
    float* __restrict__ out)
{
    const int i = blockIdx.x * 256 + threadIdx.x;
    const float d2 = diag[i] * 2.0f;
    out[i] = logf(expf(d2) + rowsum[i]) - d2;
}

extern "C" void kernel_launch(void* const* d_in, const int* in_sizes, int n_in,
                              void* d_out, int out_size, void* d_ws, size_t ws_size,
                              hipStream_t stream) {
    const float* v = (const float*)d_in[0];
    const float* u = (const float*)d_in[1];
    float* out = (float*)d_out;
    char* ws = (char*)d_ws;
    bf16* vn      = (bf16*)ws;                                  // 8 MiB
    bf16* un      = (bf16*)(ws + (size_t)8388608);              // 8 MiB
    float* diag   = (float*)(ws + (size_t)2 * 8388608);         // 32 KiB
    float* rowsum = (float*)(ws + (size_t)2 * 8388608 + 32768); // 32 KiB

    prep_kernel<<<NROWS, 256, 0, stream>>>(v, u, vn, un, diag, rowsum);
    simsum_kernel<<<1024, 512, 0, stream>>>(vn, un, rowsum);
    loss_kernel<<<NROWS / 256, 256, 0, stream>>>(diag, rowsum, out);
}